// Round 13
// baseline (273.619 us; speedup 1.0000x reference)
//
#include <hip/hip_runtime.h>

// Capsule EM routing. B=32, H=W=8, I=32 -> N=2048, O=64, P=16, routings=3.
//
// R13: shell restructure around R12's proven body. R12 counters decomposed
// accum=45us as: body VALU ~16-17us + REDUNDANT fused prologue ~10us
// (computed 8192x/pass, trans-heavy) + 2048-WG ramp (~45 WG/us fill).
// Fixes, body untouched:
//  1. prologue computed by wave 0 only -> LDS; 15 waves read (stride-64,
//     2 lanes/bank = free). 8192 -> 512 prologues/pass.
//  2. 512 WGs x 1024 thd (16 waves): block = 8 sites x 16 i; wave w owns
//     i = ig*16+w and runs R12's exact 8-site inner loop (w-row persistent
//     in VGPRs, zero vector-memory in the loop).
//  3. no LDS tree reduce: waves own disjoint (site,i) rows -> each wave
//     issues its 33 coalesced global atomicAdds directly. 2x atomic
//     traffic vs R1 (34MB, measured-safe), zero reduce barriers; ONE
//     __syncthreads total.
// Kept lessons: no unroll pragmas (R4), plain launch_bounds (R3), no LDS
// fp32 atomics (R3), no grid sync (R6/R10), plain division (R11 absmax).

#define NB 32
#define NN 2048
#define NO 64
#define NP 16
#define EPSF 1e-7f

// block tiling: 8 sites x 16 i per block; 16 blocks per batch
#define SITES_PB 8
#define IS_PB 16
#define PAIRS_PB (SITES_PB * IS_PB)   // 128 (site,i) pairs per block

#define ACC_SLOTS 33
#define ACC_PER_B (ACC_SLOTS * NO)    // 2112 floats
#define ACC_TOTAL (NB * ACC_PER_B)    // 67584 floats

template <bool FIRST>
__global__ __launch_bounds__(1024) void accum_kernel(
    const float* __restrict__ pose,        // [B][N][16]
    const float* __restrict__ act,         // [B][N]
    const float* __restrict__ wmat,        // [32][64][16]
    const float* __restrict__ beta_v,      // [64]
    const float* __restrict__ beta_a,      // [64]
    const float* __restrict__ accum_prev,  // [B][33][64] summed, or null
    float* __restrict__ accum_out,         // [B][33][64] pre-zeroed
    float inv_temp)                        // temperature of the PREV iter
{
    __shared__ float pose_s[PAIRS_PB * 16];   // 8 KB
    __shared__ float act_s[PAIRS_PB];         // 512 B
    __shared__ float stats_s[ACC_PER_B];      // 8448 B

    const int b = blockIdx.y;
    const int sg = blockIdx.x >> 1;           // site-group 0..7 (8 sites each)
    const int ig = blockIdx.x & 1;            // i-group 0..1 (16 i each)
    const int s0 = sg * SITES_PB;
    const int tid = threadIdx.x;
    const int w = tid >> 6;                   // wave 0..15 -> i = ig*16+w
    const int o = tid & 63;                   // lane = output capsule
    const int i = ig * 16 + w;

    // ---- wave-persistent w row: loaded once, before the barrier ----
    const float4* wp = (const float4*)(wmat + ((size_t)i * 64 + o) * 16);
    float4 w0 = wp[0], w1 = wp[1], w2 = wp[2], w3 = wp[3];

    // ---- stage this block's 128 (site,i) poses + acts ----
    if (tid < PAIRS_PB * 4) {                 // 512 float4 loads
        const int pr = tid >> 2, qw = tid & 3;
        const int sl = pr >> 4, li = pr & 15;
        const size_t n = (size_t)b * NN + (s0 + sl) * 32 + ig * 16 + li;
        ((float4*)pose_s)[pr * 4 + qw] = ((const float4*)(pose + n * 16))[qw];
    } else if (tid < PAIRS_PB * 4 + PAIRS_PB) {   // 128 act loads
        const int t = tid - PAIRS_PB * 4;
        const int sl = t >> 4, li = t & 15;
        act_s[t] = act[(size_t)b * NN + (s0 + sl) * 32 + ig * 16 + li];
    }

    // ---- stats of previous pass: WAVE 0 ONLY -> LDS ----
    if (!FIRST && tid < 64) {
        const float* ap = accum_prev + (size_t)b * ACC_PER_B;
        float rps = ap[32 * 64 + o];
        float rinv = 1.0f / rps;
        float logsum = 0.f;
        float mm[16], vv[16];
        #pragma unroll
        for (int p = 0; p < 16; p++) {
            float mv = ap[p * 64 + o] * rinv;
            float va = fmaxf(ap[(16 + p) * 64 + o] * rinv - mv * mv, 0.f);
            mm[p] = mv;
            vv[p] = va;
            logsum += __logf(sqrtf(va) + EPSF);
        }
        float cost = rps * (16.0f * beta_v[o] + logsum);
        float cm = cost;
        #pragma unroll
        for (int s = 32; s > 0; s >>= 1) cm += __shfl_xor(cm, s, 64);
        cm *= (1.0f / 64.0f);
        float dd = cost - cm;
        float cs = dd * dd;
        #pragma unroll
        for (int s = 32; s > 0; s >>= 1) cs += __shfl_xor(cs, s, 64);
        cs = sqrtf(cs * (1.0f / 64.0f));
        float x = inv_temp * (beta_a[o] + (cm - cost) / (cs + EPSF));
        float oa = 1.0f / (1.0f + __expf(-x));
        #pragma unroll
        for (int p = 0; p < 16; p++) stats_s[p * 64 + o] = mm[p];
        #pragma unroll
        for (int p = 0; p < 16; p++) stats_s[(16 + p) * 64 + o] = 0.5f / vv[p];
        stats_s[32 * 64 + o] = __logf(oa + EPSF) - logsum;
    }
    __syncthreads();   // staging + stats visible (the ONLY block barrier)

    float m[16], i2v[16], zzb = 0.f;
    if (!FIRST) {
        #pragma unroll
        for (int p = 0; p < 16; p++) m[p] = stats_s[p * 64 + o];
        #pragma unroll
        for (int p = 0; p < 16; p++) i2v[p] = stats_s[(16 + p) * 64 + o];
        zzb = stats_s[32 * 64 + o];
    }

    float accR = 0.f, acc1[16], acc2[16];
    #pragma unroll
    for (int p = 0; p < 16; p++) { acc1[p] = 0.f; acc2[p] = 0.f; }

    // ---- inner loop (R12-identical): zero vector-memory instructions ----
    for (int sl = 0; sl < 8; sl++) {
        const int site = s0 + sl;
        const float c0 = ((site >> 3) + 0.5f) * 0.125f;
        const float c1 = ((site & 7) + 0.5f) * 0.125f;
        const float* pr = pose_s + (sl * 16 + w) * 16;   // broadcast reads

        float v[16];
        #pragma unroll
        for (int a = 0; a < 4; a++) {
            float pa0 = pr[a * 4 + 0], pa1 = pr[a * 4 + 1];
            float pa2 = pr[a * 4 + 2], pa3 = pr[a * 4 + 3];
            v[a * 4 + 0] = pa0 * w0.x + pa1 * w1.x + pa2 * w2.x + pa3 * w3.x;
            v[a * 4 + 1] = pa0 * w0.y + pa1 * w1.y + pa2 * w2.y + pa3 * w3.y;
            v[a * 4 + 2] = pa0 * w0.z + pa1 * w1.z + pa2 * w2.z + pa3 * w3.z;
            v[a * 4 + 3] = pa0 * w0.w + pa1 * w1.w + pa2 * w2.w + pa3 * w3.w;
        }
        v[0] += c0;
        v[1] += c1;

        float rr;
        if (FIRST) {
            rr = 1.0f / 64.0f;
        } else {
            float d = zzb;
            #pragma unroll
            for (int p = 0; p < 16; p++) {
                float t = v[p] - m[p];
                d -= t * t * i2v[p];
            }
            // softmax over the 64 o-lanes
            float mx = d;
            #pragma unroll
            for (int s = 32; s > 0; s >>= 1) mx = fmaxf(mx, __shfl_xor(mx, s, 64));
            float e = __expf(d - mx);
            float sum = e;
            #pragma unroll
            for (int s = 32; s > 0; s >>= 1) sum += __shfl_xor(sum, s, 64);
            rr = e / sum;
        }
        float rp = rr * act_s[sl * 16 + w];
        accR += rp;
        #pragma unroll
        for (int p = 0; p < 16; p++) {
            acc1[p] += rp * v[p];
            acc2[p] += rp * v[p] * v[p];
        }
    }

    // ---- per-wave direct coalesced global atomics (no reduce barriers:
    //      waves own disjoint (site,i) rows of the same [33][64] sum) ----
    float* ac = accum_out + (size_t)b * ACC_PER_B;
    atomicAdd(ac + 32 * 64 + o, accR);
    #pragma unroll
    for (int p = 0; p < 16; p++) atomicAdd(ac + p * 64 + o, acc1[p]);
    #pragma unroll
    for (int p = 0; p < 16; p++) atomicAdd(ac + (16 + p) * 64 + o, acc2[p]);
}

__global__ __launch_bounds__(64) void stats_final(
    const float* __restrict__ accum,   // [B][33][64] summed
    const float* __restrict__ beta_v,  // [64]
    const float* __restrict__ beta_a,  // [64]
    float* __restrict__ out,
    float inv_temp)
{
    const int b = blockIdx.x;
    const int o = threadIdx.x;  // 64 threads = 1 wave
    const float* ac = accum + (size_t)b * ACC_PER_B;

    float rps = ac[32 * 64 + o];
    float rinv = 1.0f / rps;
    float m[16];
    float logsum = 0.f;
    #pragma unroll
    for (int p = 0; p < 16; p++) {
        float mm = ac[p * 64 + o] * rinv;
        float vv = fmaxf(ac[(16 + p) * 64 + o] * rinv - mm * mm, 0.f);
        m[p] = mm;
        logsum += __logf(sqrtf(vv) + EPSF);
    }
    float cost = rps * (16.0f * beta_v[o] + logsum);

    float cm = cost;
    #pragma unroll
    for (int s = 32; s > 0; s >>= 1) cm += __shfl_xor(cm, s, 64);
    cm *= (1.0f / 64.0f);
    float dd = cost - cm;
    float cs = dd * dd;
    #pragma unroll
    for (int s = 32; s > 0; s >>= 1) cs += __shfl_xor(cs, s, 64);
    cs = sqrtf(cs * (1.0f / 64.0f));

    float x = inv_temp * (beta_a[o] + (cm - cost) / (cs + EPSF));
    float oa = 1.0f / (1.0f + __expf(-x));

    float* op = out + ((size_t)b * 64 + o) * 16;
    #pragma unroll
    for (int p = 0; p < 16; p++) op[p] = m[p];
    out[(size_t)NB * NO * NP + (size_t)b * 64 + o] = oa;
}

extern "C" void kernel_launch(void* const* d_in, const int* in_sizes, int n_in,
                              void* d_out, int out_size, void* d_ws, size_t ws_size,
                              hipStream_t stream) {
    const float* pose   = (const float*)d_in[0];  // (32,8,8,32,4,4)
    const float* act    = (const float*)d_in[1];  // (32,8,8,32)
    const float* wmat   = (const float*)d_in[2];  // (32,64,4,4)
    const float* beta_v = (const float*)d_in[3];  // (1,64)
    const float* beta_a = (const float*)d_in[4];  // (1,64)
    float* out = (float*)d_out;
    float* ws = (float*)d_ws;

    float* a0 = ws;
    float* a1 = ws + (size_t)ACC_TOTAL;
    float* a2 = ws + 2 * (size_t)ACC_TOTAL;

    // zero the three atomic accumulators (ws is poisoned before every call)
    hipMemsetAsync(ws, 0, 3 * (size_t)ACC_TOTAL * sizeof(float), stream);

    dim3 grid(16, NB);   // 512 WGs x 1024 thd
    accum_kernel<true ><<<grid, 1024, 0, stream>>>(pose, act, wmat, beta_v, beta_a,
                                                   nullptr, a0, 0.0f);
    accum_kernel<false><<<grid, 1024, 0, stream>>>(pose, act, wmat, beta_v, beta_a,
                                                   a0, a1, 1.0f);
    accum_kernel<false><<<grid, 1024, 0, stream>>>(pose, act, wmat, beta_v, beta_a,
                                                   a1, a2, 2.0f);
    stats_final<<<NB, 64, 0, stream>>>(a2, beta_v, beta_a, out, 3.0f);
}

// Round 14
// 156.253 us; speedup vs baseline: 1.7511x; 1.7511x over previous
//
#include <hip/hip_runtime.h>

// Capsule EM routing. B=32, H=W=8, I=32 -> N=2048, O=64, P=16, routings=3.
//
// R14: R13's shape with the proven reduction. R13 isolated its own
// regression: per-wave direct global atomics quadrupled atomic traffic
// (WRITE 16.9->67.6MB) and put 256 waves/batch in same-address contention
// -> serialization (+30us). The shape itself (512 WGs x 1024 thd,
// w-persistent body, wave0-only prologue) compiled clean (64 VGPR, no
// spill). Ramp model now quantitative: dispatch ~= ramp + block_dur with
// ramp(2048WG) ~= 29us (R1: 29+13=42; R12: 29+16=45) and fixed(512WG) ~=
// 12us (R9 probe3) -- 2048-WG shapes have a ~40us floor, 512-WG does not.
// This round: keep R13's block tiling (8 sites x 16 i, wave w owns i),
// wave0-only prologue into a SEPARATE stats_s (no reuse race), R12's exact
// zero-vmem body, then R5's barrier-sequenced in-place adds into buf[4]
// (grp = w>>2, 4 rounds) + ONE cooperative block flush (~2 coalesced
// atomics/thread, one [33][64] per block = 4.3MB/pass, 16 adds/addr/batch;
// R1 ran 64/addr fine). LDS 50.7KB -> 2 blocks/CU, 32 waves/CU.
// Kept lessons: no unroll pragmas (R4), plain launch_bounds (R3), no LDS
// fp32 atomics (R3), no grid sync (R6/R10), stable (v-m)^2 math (R11).

#define NB 32
#define NN 2048
#define NO 64
#define NP 16
#define EPSF 1e-7f

// block tiling: 8 sites x 16 i per block; 16 blocks per batch
#define SITES_PB 8
#define IS_PB 16
#define PAIRS_PB (SITES_PB * IS_PB)   // 128 (site,i) pairs per block

#define ACC_SLOTS 33
#define ACC_PER_B (ACC_SLOTS * NO)    // 2112 floats
#define ACC_TOTAL (NB * ACC_PER_B)    // 67584 floats

template <bool FIRST>
__global__ __launch_bounds__(1024) void accum_kernel(
    const float* __restrict__ pose,        // [B][N][16]
    const float* __restrict__ act,         // [B][N]
    const float* __restrict__ wmat,        // [32][64][16]
    const float* __restrict__ beta_v,      // [64]
    const float* __restrict__ beta_a,      // [64]
    const float* __restrict__ accum_prev,  // [B][33][64] summed, or null
    float* __restrict__ accum_out,         // [B][33][64] pre-zeroed
    float inv_temp)                        // temperature of the PREV iter
{
    __shared__ float pose_s[PAIRS_PB * 16];   // 8 KB
    __shared__ float act_s[PAIRS_PB];         // 512 B
    __shared__ float stats_s[ACC_PER_B];      // 8448 B
    __shared__ float buf[4][ACC_PER_B];       // 33.8 KB reduce buffers

    const int b = blockIdx.y;
    const int sg = blockIdx.x >> 1;           // site-group 0..7 (8 sites)
    const int ig = blockIdx.x & 1;            // i-group 0..1 (16 i)
    const int s0 = sg * SITES_PB;
    const int tid = threadIdx.x;
    const int w = tid >> 6;                   // wave 0..15 -> i = ig*16+w
    const int o = tid & 63;                   // lane = output capsule
    const int i = ig * 16 + w;
    const int grp = w >> 2, wvin = w & 3;     // reduce grouping

    // ---- wave-persistent w row: loaded once ----
    const float4* wp = (const float4*)(wmat + ((size_t)i * 64 + o) * 16);
    float4 w0 = wp[0], w1 = wp[1], w2 = wp[2], w3 = wp[3];

    // ---- stage this block's 128 (site,i) poses + acts ----
    if (tid < PAIRS_PB * 4) {                 // 512 float4 loads
        const int pr = tid >> 2, qw = tid & 3;
        const int sl = pr >> 4, li = pr & 15;
        const size_t n = (size_t)b * NN + (s0 + sl) * 32 + ig * 16 + li;
        ((float4*)pose_s)[pr * 4 + qw] = ((const float4*)(pose + n * 16))[qw];
    } else if (tid < PAIRS_PB * 4 + PAIRS_PB) {   // 128 act loads
        const int t = tid - PAIRS_PB * 4;
        const int sl = t >> 4, li = t & 15;
        act_s[t] = act[(size_t)b * NN + (s0 + sl) * 32 + ig * 16 + li];
    }

    // ---- stats of previous pass: WAVE 0 ONLY -> stats_s ----
    if (!FIRST && tid < 64) {
        const float* ap = accum_prev + (size_t)b * ACC_PER_B;
        float rps = ap[32 * 64 + o];
        float rinv = 1.0f / rps;
        float logsum = 0.f;
        float mm[16], vv[16];
        #pragma unroll
        for (int p = 0; p < 16; p++) {
            float mv = ap[p * 64 + o] * rinv;
            float va = fmaxf(ap[(16 + p) * 64 + o] * rinv - mv * mv, 0.f);
            mm[p] = mv;
            vv[p] = va;
            logsum += __logf(sqrtf(va) + EPSF);
        }
        float cost = rps * (16.0f * beta_v[o] + logsum);
        float cm = cost;
        #pragma unroll
        for (int s = 32; s > 0; s >>= 1) cm += __shfl_xor(cm, s, 64);
        cm *= (1.0f / 64.0f);
        float dd = cost - cm;
        float cs = dd * dd;
        #pragma unroll
        for (int s = 32; s > 0; s >>= 1) cs += __shfl_xor(cs, s, 64);
        cs = sqrtf(cs * (1.0f / 64.0f));
        float x = inv_temp * (beta_a[o] + (cm - cost) / (cs + EPSF));
        float oa = 1.0f / (1.0f + __expf(-x));
        #pragma unroll
        for (int p = 0; p < 16; p++) stats_s[p * 64 + o] = mm[p];
        #pragma unroll
        for (int p = 0; p < 16; p++) stats_s[(16 + p) * 64 + o] = 0.5f / vv[p];
        stats_s[32 * 64 + o] = __logf(oa + EPSF) - logsum;
    }
    __syncthreads();   // staging + stats visible

    float m[16], i2v[16], zzb = 0.f;
    if (!FIRST) {
        #pragma unroll
        for (int p = 0; p < 16; p++) m[p] = stats_s[p * 64 + o];
        #pragma unroll
        for (int p = 0; p < 16; p++) i2v[p] = stats_s[(16 + p) * 64 + o];
        zzb = stats_s[32 * 64 + o];
    }

    float accR = 0.f, acc1[16], acc2[16];
    #pragma unroll
    for (int p = 0; p < 16; p++) { acc1[p] = 0.f; acc2[p] = 0.f; }

    // ---- inner loop (R12-identical): zero vector-memory instructions ----
    for (int sl = 0; sl < 8; sl++) {
        const int site = s0 + sl;
        const float c0 = ((site >> 3) + 0.5f) * 0.125f;
        const float c1 = ((site & 7) + 0.5f) * 0.125f;
        const float* pr = pose_s + (sl * 16 + w) * 16;   // broadcast reads

        float v[16];
        #pragma unroll
        for (int a = 0; a < 4; a++) {
            float pa0 = pr[a * 4 + 0], pa1 = pr[a * 4 + 1];
            float pa2 = pr[a * 4 + 2], pa3 = pr[a * 4 + 3];
            v[a * 4 + 0] = pa0 * w0.x + pa1 * w1.x + pa2 * w2.x + pa3 * w3.x;
            v[a * 4 + 1] = pa0 * w0.y + pa1 * w1.y + pa2 * w2.y + pa3 * w3.y;
            v[a * 4 + 2] = pa0 * w0.z + pa1 * w1.z + pa2 * w2.z + pa3 * w3.z;
            v[a * 4 + 3] = pa0 * w0.w + pa1 * w1.w + pa2 * w2.w + pa3 * w3.w;
        }
        v[0] += c0;
        v[1] += c1;

        float rr;
        if (FIRST) {
            rr = 1.0f / 64.0f;
        } else {
            float d = zzb;
            #pragma unroll
            for (int p = 0; p < 16; p++) {
                float t = v[p] - m[p];
                d -= t * t * i2v[p];
            }
            // softmax over the 64 o-lanes
            float mx = d;
            #pragma unroll
            for (int s = 32; s > 0; s >>= 1) mx = fmaxf(mx, __shfl_xor(mx, s, 64));
            float e = __expf(d - mx);
            float sum = e;
            #pragma unroll
            for (int s = 32; s > 0; s >>= 1) sum += __shfl_xor(sum, s, 64);
            rr = e / sum;
        }
        float rp = rr * act_s[sl * 16 + w];
        accR += rp;
        #pragma unroll
        for (int p = 0; p < 16; p++) {
            acc1[p] += rp * v[p];
            acc2[p] += rp * v[p] * v[p];
        }
    }

    // ---- R5-proven reduce: barrier-sequenced in-place adds per group ----
    if (wvin == 3) {
        float* r = buf[grp];
        r[32 * 64 + o] = accR;
        #pragma unroll
        for (int p = 0; p < 16; p++) r[p * 64 + o] = acc1[p];
        #pragma unroll
        for (int p = 0; p < 16; p++) r[(16 + p) * 64 + o] = acc2[p];
    }
    __syncthreads();
    if (wvin == 2) {
        float* r = buf[grp];
        r[32 * 64 + o] += accR;
        #pragma unroll
        for (int p = 0; p < 16; p++) r[p * 64 + o] += acc1[p];
        #pragma unroll
        for (int p = 0; p < 16; p++) r[(16 + p) * 64 + o] += acc2[p];
    }
    __syncthreads();
    if (wvin == 1) {
        float* r = buf[grp];
        r[32 * 64 + o] += accR;
        #pragma unroll
        for (int p = 0; p < 16; p++) r[p * 64 + o] += acc1[p];
        #pragma unroll
        for (int p = 0; p < 16; p++) r[(16 + p) * 64 + o] += acc2[p];
    }
    __syncthreads();
    if (wvin == 0) {
        float* r = buf[grp];
        r[32 * 64 + o] += accR;
        #pragma unroll
        for (int p = 0; p < 16; p++) r[p * 64 + o] += acc1[p];
        #pragma unroll
        for (int p = 0; p < 16; p++) r[(16 + p) * 64 + o] += acc2[p];
    }
    __syncthreads();

    // ---- ONE cooperative flush: ~2 coalesced atomics per thread ----
    float* ac = accum_out + (size_t)b * ACC_PER_B;
    for (int j = tid; j < ACC_PER_B; j += 1024)
        atomicAdd(ac + j, buf[0][j] + buf[1][j] + buf[2][j] + buf[3][j]);
}

__global__ __launch_bounds__(64) void stats_final(
    const float* __restrict__ accum,   // [B][33][64] summed
    const float* __restrict__ beta_v,  // [64]
    const float* __restrict__ beta_a,  // [64]
    float* __restrict__ out,
    float inv_temp)
{
    const int b = blockIdx.x;
    const int o = threadIdx.x;  // 64 threads = 1 wave
    const float* ac = accum + (size_t)b * ACC_PER_B;

    float rps = ac[32 * 64 + o];
    float rinv = 1.0f / rps;
    float m[16];
    float logsum = 0.f;
    #pragma unroll
    for (int p = 0; p < 16; p++) {
        float mm = ac[p * 64 + o] * rinv;
        float vv = fmaxf(ac[(16 + p) * 64 + o] * rinv - mm * mm, 0.f);
        m[p] = mm;
        logsum += __logf(sqrtf(vv) + EPSF);
    }
    float cost = rps * (16.0f * beta_v[o] + logsum);

    float cm = cost;
    #pragma unroll
    for (int s = 32; s > 0; s >>= 1) cm += __shfl_xor(cm, s, 64);
    cm *= (1.0f / 64.0f);
    float dd = cost - cm;
    float cs = dd * dd;
    #pragma unroll
    for (int s = 32; s > 0; s >>= 1) cs += __shfl_xor(cs, s, 64);
    cs = sqrtf(cs * (1.0f / 64.0f));

    float x = inv_temp * (beta_a[o] + (cm - cost) / (cs + EPSF));
    float oa = 1.0f / (1.0f + __expf(-x));

    float* op = out + ((size_t)b * 64 + o) * 16;
    #pragma unroll
    for (int p = 0; p < 16; p++) op[p] = m[p];
    out[(size_t)NB * NO * NP + (size_t)b * 64 + o] = oa;
}

extern "C" void kernel_launch(void* const* d_in, const int* in_sizes, int n_in,
                              void* d_out, int out_size, void* d_ws, size_t ws_size,
                              hipStream_t stream) {
    const float* pose   = (const float*)d_in[0];  // (32,8,8,32,4,4)
    const float* act    = (const float*)d_in[1];  // (32,8,8,32)
    const float* wmat   = (const float*)d_in[2];  // (32,64,4,4)
    const float* beta_v = (const float*)d_in[3];  // (1,64)
    const float* beta_a = (const float*)d_in[4];  // (1,64)
    float* out = (float*)d_out;
    float* ws = (float*)d_ws;

    float* a0 = ws;
    float* a1 = ws + (size_t)ACC_TOTAL;
    float* a2 = ws + 2 * (size_t)ACC_TOTAL;

    // zero the three atomic accumulators (ws is poisoned before every call)
    hipMemsetAsync(ws, 0, 3 * (size_t)ACC_TOTAL * sizeof(float), stream);

    dim3 grid(16, NB);   // 512 WGs x 1024 thd
    accum_kernel<true ><<<grid, 1024, 0, stream>>>(pose, act, wmat, beta_v, beta_a,
                                                   nullptr, a0, 0.0f);
    accum_kernel<false><<<grid, 1024, 0, stream>>>(pose, act, wmat, beta_v, beta_a,
                                                   a0, a1, 1.0f);
    accum_kernel<false><<<grid, 1024, 0, stream>>>(pose, act, wmat, beta_v, beta_a,
                                                   a1, a2, 2.0f);
    stats_final<<<NB, 64, 0, stream>>>(a2, beta_v, beta_a, out, 3.0f);
}

// Round 15
// 146.698 us; speedup vs baseline: 1.8652x; 1.0651x over previous
//
#include <hip/hip_runtime.h>

// Capsule EM routing. B=32, H=W=8, I=32 -> N=2048, O=64, P=16, routings=3.
//
// R15: strip the DS pipe. R14 (512WG x 1024, w-persistent, wave0 prologue,
// proven reduce) landed 50.8us/accum; audit: VALU ~8-9us/SIMD, fixed ~12us,
// and the DS pipe carries ~29+ ops per wave-iter (16 pose broadcast reads +
// 12 softmax shuffles, plus possible in-loop stats_s rereads at 64 VGPR) --
// the biggest unmodeled consumer, hit twice per iter on the critical path.
// Cuts (shell identical to R14):
//  1. pose/act by wave-uniform SCALAR loads (readfirstlane base ->
//     s_load_dwordx4, SMEM pipe): pose/act LDS staging deleted.
//  2. softmax max-hoist: softmax is shift-invariant -> subtract a per-pass
//     per-lane constant zzbK = zzb - max_o(zzb) (one extra shuffle-max in
//     the wave0 prologue), exponent = zzbK - M <= 0 (no overflow; underflow
//     benign), rr = e / fmaxf(sum,1e-30) guards all-underflow. Removes the
//     per-iter 6-step shuffle-max + 6 fmax entirely.
//  => DS ops/iter ~29 -> ~6 (sum shuffles only).
// Kept lessons: no unroll pragmas (R4), plain launch_bounds (R3), no LDS
// fp32 atomics (R3), no grid sync (R6/R10), one coop atomic flush (R13:
// per-wave direct atomics serialize), stable (v-m)^2 math (R11).

#define NB 32
#define NN 2048
#define NO 64
#define NP 16
#define EPSF 1e-7f

// block tiling: 8 sites x 16 i per block; 16 blocks per batch
#define SITES_PB 8
#define IS_PB 16

#define ACC_SLOTS 33
#define ACC_PER_B (ACC_SLOTS * NO)    // 2112 floats
#define ACC_TOTAL (NB * ACC_PER_B)    // 67584 floats

template <bool FIRST>
__global__ __launch_bounds__(1024) void accum_kernel(
    const float* __restrict__ pose,        // [B][N][16]
    const float* __restrict__ act,         // [B][N]
    const float* __restrict__ wmat,        // [32][64][16]
    const float* __restrict__ beta_v,      // [64]
    const float* __restrict__ beta_a,      // [64]
    const float* __restrict__ accum_prev,  // [B][33][64] summed, or null
    float* __restrict__ accum_out,         // [B][33][64] pre-zeroed
    float inv_temp)                        // temperature of the PREV iter
{
    __shared__ float stats_s[ACC_PER_B];      // 8448 B (slot32 = zzb - K)
    __shared__ float buf[4][ACC_PER_B];       // 33.8 KB reduce buffers

    const int b = blockIdx.y;
    const int sg = blockIdx.x >> 1;           // site-group 0..7 (8 sites)
    const int ig = blockIdx.x & 1;            // i-group 0..1 (16 i)
    const int s0 = sg * SITES_PB;
    const int tid = threadIdx.x;
    const int w = tid >> 6;                   // wave 0..15 -> i = ig*16+w
    const int o = tid & 63;                   // lane = output capsule
    const int i = ig * 16 + w;
    const int grp = w >> 2, wvin = w & 3;     // reduce grouping

    // ---- wave-persistent w row: loaded once ----
    const float4* wp = (const float4*)(wmat + ((size_t)i * 64 + o) * 16);
    float4 w0 = wp[0], w1 = wp[1], w2 = wp[2], w3 = wp[3];

    // ---- stats of previous pass: WAVE 0 ONLY -> stats_s ----
    if (!FIRST && tid < 64) {
        const float* ap = accum_prev + (size_t)b * ACC_PER_B;
        float rps = ap[32 * 64 + o];
        float rinv = 1.0f / rps;
        float logsum = 0.f;
        float mm[16], vv[16];
        #pragma unroll
        for (int p = 0; p < 16; p++) {
            float mv = ap[p * 64 + o] * rinv;
            float va = fmaxf(ap[(16 + p) * 64 + o] * rinv - mv * mv, 0.f);
            mm[p] = mv;
            vv[p] = va;
            logsum += __logf(sqrtf(va) + EPSF);
        }
        float cost = rps * (16.0f * beta_v[o] + logsum);
        float cm = cost;
        #pragma unroll
        for (int s = 32; s > 0; s >>= 1) cm += __shfl_xor(cm, s, 64);
        cm *= (1.0f / 64.0f);
        float dd = cost - cm;
        float cs = dd * dd;
        #pragma unroll
        for (int s = 32; s > 0; s >>= 1) cs += __shfl_xor(cs, s, 64);
        cs = sqrtf(cs * (1.0f / 64.0f));
        float x = inv_temp * (beta_a[o] + (cm - cost) / (cs + EPSF));
        float oa = 1.0f / (1.0f + __expf(-x));
        float zzb = __logf(oa + EPSF) - logsum;
        // softmax shift constant: K = max over the 64 o-lanes of zzb
        float K = zzb;
        #pragma unroll
        for (int s = 32; s > 0; s >>= 1) K = fmaxf(K, __shfl_xor(K, s, 64));
        #pragma unroll
        for (int p = 0; p < 16; p++) stats_s[p * 64 + o] = mm[p];
        #pragma unroll
        for (int p = 0; p < 16; p++) stats_s[(16 + p) * 64 + o] = 0.5f / vv[p];
        stats_s[32 * 64 + o] = zzb - K;
    }
    __syncthreads();   // stats visible

    float m[16], i2v[16], zzbK = 0.f;
    if (!FIRST) {
        #pragma unroll
        for (int p = 0; p < 16; p++) m[p] = stats_s[p * 64 + o];
        #pragma unroll
        for (int p = 0; p < 16; p++) i2v[p] = stats_s[(16 + p) * 64 + o];
        zzbK = stats_s[32 * 64 + o];
    }

    float accR = 0.f, acc1[16], acc2[16];
    #pragma unroll
    for (int p = 0; p < 16; p++) { acc1[p] = 0.f; acc2[p] = 0.f; }

    // wave-uniform base index for scalar pose/act loads
    const int base_n = __builtin_amdgcn_readfirstlane(s0 * 32 + ig * 16 + w);
    const float* pose_b = pose + (size_t)b * NN * 16;
    const float* act_b  = act + (size_t)b * NN;

    // ---- inner loop: zero LDS reads; pose/act on the SMEM pipe ----
    for (int sl = 0; sl < 8; sl++) {
        const int site = s0 + sl;
        const float c0 = ((site >> 3) + 0.5f) * 0.125f;
        const float c1 = ((site & 7) + 0.5f) * 0.125f;
        const int n = base_n + sl * 32;                 // wave-uniform
        const float4* pr4 = (const float4*)(pose_b + (size_t)n * 16);
        const float av = act_b[n];                      // scalar load

        float v[16];
        #pragma unroll
        for (int a = 0; a < 4; a++) {
            float4 pa = pr4[a];                         // s_load_dwordx4
            v[a * 4 + 0] = pa.x * w0.x + pa.y * w1.x + pa.z * w2.x + pa.w * w3.x;
            v[a * 4 + 1] = pa.x * w0.y + pa.y * w1.y + pa.z * w2.y + pa.w * w3.y;
            v[a * 4 + 2] = pa.x * w0.z + pa.y * w1.z + pa.z * w2.z + pa.w * w3.z;
            v[a * 4 + 3] = pa.x * w0.w + pa.y * w1.w + pa.z * w2.w + pa.w * w3.w;
        }
        v[0] += c0;
        v[1] += c1;

        float rr;
        if (FIRST) {
            rr = 1.0f / 64.0f;
        } else {
            float d = zzbK;
            #pragma unroll
            for (int p = 0; p < 16; p++) {
                float t = v[p] - m[p];
                d -= t * t * i2v[p];
            }
            // shifted softmax: exponent <= 0 by construction (no max pass)
            float e = __expf(d);
            float sum = e;
            #pragma unroll
            for (int s = 32; s > 0; s >>= 1) sum += __shfl_xor(sum, s, 64);
            rr = e / fmaxf(sum, 1e-30f);
        }
        float rp = rr * av;
        accR += rp;
        #pragma unroll
        for (int p = 0; p < 16; p++) {
            acc1[p] += rp * v[p];
            acc2[p] += rp * v[p] * v[p];
        }
    }

    // ---- R5-proven reduce: barrier-sequenced in-place adds per group ----
    if (wvin == 3) {
        float* r = buf[grp];
        r[32 * 64 + o] = accR;
        #pragma unroll
        for (int p = 0; p < 16; p++) r[p * 64 + o] = acc1[p];
        #pragma unroll
        for (int p = 0; p < 16; p++) r[(16 + p) * 64 + o] = acc2[p];
    }
    __syncthreads();
    if (wvin == 2) {
        float* r = buf[grp];
        r[32 * 64 + o] += accR;
        #pragma unroll
        for (int p = 0; p < 16; p++) r[p * 64 + o] += acc1[p];
        #pragma unroll
        for (int p = 0; p < 16; p++) r[(16 + p) * 64 + o] += acc2[p];
    }
    __syncthreads();
    if (wvin == 1) {
        float* r = buf[grp];
        r[32 * 64 + o] += accR;
        #pragma unroll
        for (int p = 0; p < 16; p++) r[p * 64 + o] += acc1[p];
        #pragma unroll
        for (int p = 0; p < 16; p++) r[(16 + p) * 64 + o] += acc2[p];
    }
    __syncthreads();
    if (wvin == 0) {
        float* r = buf[grp];
        r[32 * 64 + o] += accR;
        #pragma unroll
        for (int p = 0; p < 16; p++) r[p * 64 + o] += acc1[p];
        #pragma unroll
        for (int p = 0; p < 16; p++) r[(16 + p) * 64 + o] += acc2[p];
    }
    __syncthreads();

    // ---- ONE cooperative flush: ~2 coalesced atomics per thread ----
    float* ac = accum_out + (size_t)b * ACC_PER_B;
    for (int j = tid; j < ACC_PER_B; j += 1024)
        atomicAdd(ac + j, buf[0][j] + buf[1][j] + buf[2][j] + buf[3][j]);
}

__global__ __launch_bounds__(64) void stats_final(
    const float* __restrict__ accum,   // [B][33][64] summed
    const float* __restrict__ beta_v,  // [64]
    const float* __restrict__ beta_a,  // [64]
    float* __restrict__ out,
    float inv_temp)
{
    const int b = blockIdx.x;
    const int o = threadIdx.x;  // 64 threads = 1 wave
    const float* ac = accum + (size_t)b * ACC_PER_B;

    float rps = ac[32 * 64 + o];
    float rinv = 1.0f / rps;
    float m[16];
    float logsum = 0.f;
    #pragma unroll
    for (int p = 0; p < 16; p++) {
        float mm = ac[p * 64 + o] * rinv;
        float vv = fmaxf(ac[(16 + p) * 64 + o] * rinv - mm * mm, 0.f);
        m[p] = mm;
        logsum += __logf(sqrtf(vv) + EPSF);
    }
    float cost = rps * (16.0f * beta_v[o] + logsum);

    float cm = cost;
    #pragma unroll
    for (int s = 32; s > 0; s >>= 1) cm += __shfl_xor(cm, s, 64);
    cm *= (1.0f / 64.0f);
    float dd = cost - cm;
    float cs = dd * dd;
    #pragma unroll
    for (int s = 32; s > 0; s >>= 1) cs += __shfl_xor(cs, s, 64);
    cs = sqrtf(cs * (1.0f / 64.0f));

    float x = inv_temp * (beta_a[o] + (cm - cost) / (cs + EPSF));
    float oa = 1.0f / (1.0f + __expf(-x));

    float* op = out + ((size_t)b * 64 + o) * 16;
    #pragma unroll
    for (int p = 0; p < 16; p++) op[p] = m[p];
    out[(size_t)NB * NO * NP + (size_t)b * 64 + o] = oa;
}

extern "C" void kernel_launch(void* const* d_in, const int* in_sizes, int n_in,
                              void* d_out, int out_size, void* d_ws, size_t ws_size,
                              hipStream_t stream) {
    const float* pose   = (const float*)d_in[0];  // (32,8,8,32,4,4)
    const float* act    = (const float*)d_in[1];  // (32,8,8,32)
    const float* wmat   = (const float*)d_in[2];  // (32,64,4,4)
    const float* beta_v = (const float*)d_in[3];  // (1,64)
    const float* beta_a = (const float*)d_in[4];  // (1,64)
    float* out = (float*)d_out;
    float* ws = (float*)d_ws;

    float* a0 = ws;
    float* a1 = ws + (size_t)ACC_TOTAL;
    float* a2 = ws + 2 * (size_t)ACC_TOTAL;

    // zero the three atomic accumulators (ws is poisoned before every call)
    hipMemsetAsync(ws, 0, 3 * (size_t)ACC_TOTAL * sizeof(float), stream);

    dim3 grid(16, NB);   // 512 WGs x 1024 thd
    accum_kernel<true ><<<grid, 1024, 0, stream>>>(pose, act, wmat, beta_v, beta_a,
                                                   nullptr, a0, 0.0f);
    accum_kernel<false><<<grid, 1024, 0, stream>>>(pose, act, wmat, beta_v, beta_a,
                                                   a0, a1, 1.0f);
    accum_kernel<false><<<grid, 1024, 0, stream>>>(pose, act, wmat, beta_v, beta_a,
                                                   a1, a2, 2.0f);
    stats_final<<<NB, 64, 0, stream>>>(a2, beta_v, beta_a, out, 3.0f);
}

// Round 16
// 146.059 us; speedup vs baseline: 1.8733x; 1.0044x over previous
//
#include <hip/hip_runtime.h>

// Capsule EM routing. B=32, H=W=8, I=32 -> N=2048, O=64, P=16, routings=3.
//
// R16: R15 + software-pipelined scalar loads. R15 (pose/act on SMEM pipe,
// softmax max-hoist, 512WG x 1024, w-persistent, wave0 prologue, proven
// reduce) = 39.8us/accum, absmax 4.9e-4. Budget: fixed ~12-13us, VALU issue
// ~15us, stall ~12us. Last unruled single-resource stall: the per-iter
// s_load_dwordx4 pose fetch is issued at the top of each iteration and
// consumed immediately (~200cy L2 latency exposed; 32 waves/CU pile onto
// the SMEM pipe in loose lockstep). Fix: branch-free next-iter prefetch
// into a second scalar register set ((sl+1)&7 wrap) -- latency hides under
// the previous iteration's ~350cy of FMA/softmax. +~17 SGPRs (free), zero
// VGPR/LDS delta. Everything else bit-identical to R15.
// Kept lessons: no unroll pragmas (R4), plain launch_bounds (R3), no LDS
// fp32 atomics (R3), no grid sync (R6/R10), one coop atomic flush (R13),
// stable (v-m)^2 math (R11), max-hoisted softmax (R15, absmax-verified).

#define NB 32
#define NN 2048
#define NO 64
#define NP 16
#define EPSF 1e-7f

// block tiling: 8 sites x 16 i per block; 16 blocks per batch
#define SITES_PB 8
#define IS_PB 16

#define ACC_SLOTS 33
#define ACC_PER_B (ACC_SLOTS * NO)    // 2112 floats
#define ACC_TOTAL (NB * ACC_PER_B)    // 67584 floats

template <bool FIRST>
__global__ __launch_bounds__(1024) void accum_kernel(
    const float* __restrict__ pose,        // [B][N][16]
    const float* __restrict__ act,         // [B][N]
    const float* __restrict__ wmat,        // [32][64][16]
    const float* __restrict__ beta_v,      // [64]
    const float* __restrict__ beta_a,      // [64]
    const float* __restrict__ accum_prev,  // [B][33][64] summed, or null
    float* __restrict__ accum_out,         // [B][33][64] pre-zeroed
    float inv_temp)                        // temperature of the PREV iter
{
    __shared__ float stats_s[ACC_PER_B];      // 8448 B (slot32 = zzb - K)
    __shared__ float buf[4][ACC_PER_B];       // 33.8 KB reduce buffers

    const int b = blockIdx.y;
    const int sg = blockIdx.x >> 1;           // site-group 0..7 (8 sites)
    const int ig = blockIdx.x & 1;            // i-group 0..1 (16 i)
    const int s0 = sg * SITES_PB;
    const int tid = threadIdx.x;
    const int w = tid >> 6;                   // wave 0..15 -> i = ig*16+w
    const int o = tid & 63;                   // lane = output capsule
    const int i = ig * 16 + w;
    const int grp = w >> 2, wvin = w & 3;     // reduce grouping

    // ---- wave-persistent w row: loaded once ----
    const float4* wp = (const float4*)(wmat + ((size_t)i * 64 + o) * 16);
    float4 w0 = wp[0], w1 = wp[1], w2 = wp[2], w3 = wp[3];

    // ---- stats of previous pass: WAVE 0 ONLY -> stats_s ----
    if (!FIRST && tid < 64) {
        const float* ap = accum_prev + (size_t)b * ACC_PER_B;
        float rps = ap[32 * 64 + o];
        float rinv = 1.0f / rps;
        float logsum = 0.f;
        float mm[16], vv[16];
        #pragma unroll
        for (int p = 0; p < 16; p++) {
            float mv = ap[p * 64 + o] * rinv;
            float va = fmaxf(ap[(16 + p) * 64 + o] * rinv - mv * mv, 0.f);
            mm[p] = mv;
            vv[p] = va;
            logsum += __logf(sqrtf(va) + EPSF);
        }
        float cost = rps * (16.0f * beta_v[o] + logsum);
        float cm = cost;
        #pragma unroll
        for (int s = 32; s > 0; s >>= 1) cm += __shfl_xor(cm, s, 64);
        cm *= (1.0f / 64.0f);
        float dd = cost - cm;
        float cs = dd * dd;
        #pragma unroll
        for (int s = 32; s > 0; s >>= 1) cs += __shfl_xor(cs, s, 64);
        cs = sqrtf(cs * (1.0f / 64.0f));
        float x = inv_temp * (beta_a[o] + (cm - cost) / (cs + EPSF));
        float oa = 1.0f / (1.0f + __expf(-x));
        float zzb = __logf(oa + EPSF) - logsum;
        // softmax shift constant: K = max over the 64 o-lanes of zzb
        float K = zzb;
        #pragma unroll
        for (int s = 32; s > 0; s >>= 1) K = fmaxf(K, __shfl_xor(K, s, 64));
        #pragma unroll
        for (int p = 0; p < 16; p++) stats_s[p * 64 + o] = mm[p];
        #pragma unroll
        for (int p = 0; p < 16; p++) stats_s[(16 + p) * 64 + o] = 0.5f / vv[p];
        stats_s[32 * 64 + o] = zzb - K;
    }
    __syncthreads();   // stats visible

    float m[16], i2v[16], zzbK = 0.f;
    if (!FIRST) {
        #pragma unroll
        for (int p = 0; p < 16; p++) m[p] = stats_s[p * 64 + o];
        #pragma unroll
        for (int p = 0; p < 16; p++) i2v[p] = stats_s[(16 + p) * 64 + o];
        zzbK = stats_s[32 * 64 + o];
    }

    float accR = 0.f, acc1[16], acc2[16];
    #pragma unroll
    for (int p = 0; p < 16; p++) { acc1[p] = 0.f; acc2[p] = 0.f; }

    // wave-uniform base index for scalar pose/act loads
    const int base_n = __builtin_amdgcn_readfirstlane(s0 * 32 + ig * 16 + w);
    const float* pose_b = pose + (size_t)b * NN * 16;
    const float* act_b  = act + (size_t)b * NN;

    // ---- software-pipelined inner loop: next-iter scalar loads issued
    //      before the current iteration's compute (branch-free wrap) ----
    float4 cA, cB, cC, cD;
    float cav;
    {
        const float4* pr4 = (const float4*)(pose_b + (size_t)base_n * 16);
        cA = pr4[0]; cB = pr4[1]; cC = pr4[2]; cD = pr4[3];
        cav = act_b[base_n];
    }
    for (int sl = 0; sl < 8; sl++) {
        // prefetch iteration sl+1 (wraps to sl=0 data on the last iter)
        const int nn = base_n + (((sl + 1) & 7) * 32);
        const float4* nr4 = (const float4*)(pose_b + (size_t)nn * 16);
        float4 nA = nr4[0], nB = nr4[1], nC = nr4[2], nD = nr4[3];
        float nav = act_b[nn];

        const int site = s0 + sl;
        const float c0 = ((site >> 3) + 0.5f) * 0.125f;
        const float c1 = ((site & 7) + 0.5f) * 0.125f;

        float v[16];
        {
            float4 pa = cA;
            v[0] = pa.x * w0.x + pa.y * w1.x + pa.z * w2.x + pa.w * w3.x;
            v[1] = pa.x * w0.y + pa.y * w1.y + pa.z * w2.y + pa.w * w3.y;
            v[2] = pa.x * w0.z + pa.y * w1.z + pa.z * w2.z + pa.w * w3.z;
            v[3] = pa.x * w0.w + pa.y * w1.w + pa.z * w2.w + pa.w * w3.w;
            pa = cB;
            v[4] = pa.x * w0.x + pa.y * w1.x + pa.z * w2.x + pa.w * w3.x;
            v[5] = pa.x * w0.y + pa.y * w1.y + pa.z * w2.y + pa.w * w3.y;
            v[6] = pa.x * w0.z + pa.y * w1.z + pa.z * w2.z + pa.w * w3.z;
            v[7] = pa.x * w0.w + pa.y * w1.w + pa.z * w2.w + pa.w * w3.w;
            pa = cC;
            v[8]  = pa.x * w0.x + pa.y * w1.x + pa.z * w2.x + pa.w * w3.x;
            v[9]  = pa.x * w0.y + pa.y * w1.y + pa.z * w2.y + pa.w * w3.y;
            v[10] = pa.x * w0.z + pa.y * w1.z + pa.z * w2.z + pa.w * w3.z;
            v[11] = pa.x * w0.w + pa.y * w1.w + pa.z * w2.w + pa.w * w3.w;
            pa = cD;
            v[12] = pa.x * w0.x + pa.y * w1.x + pa.z * w2.x + pa.w * w3.x;
            v[13] = pa.x * w0.y + pa.y * w1.y + pa.z * w2.y + pa.w * w3.y;
            v[14] = pa.x * w0.z + pa.y * w1.z + pa.z * w2.z + pa.w * w3.z;
            v[15] = pa.x * w0.w + pa.y * w1.w + pa.z * w2.w + pa.w * w3.w;
        }
        v[0] += c0;
        v[1] += c1;

        float rr;
        if (FIRST) {
            rr = 1.0f / 64.0f;
        } else {
            float d = zzbK;
            #pragma unroll
            for (int p = 0; p < 16; p++) {
                float t = v[p] - m[p];
                d -= t * t * i2v[p];
            }
            // shifted softmax: exponent <= 0 by construction (no max pass)
            float e = __expf(d);
            float sum = e;
            #pragma unroll
            for (int s = 32; s > 0; s >>= 1) sum += __shfl_xor(sum, s, 64);
            rr = e / fmaxf(sum, 1e-30f);
        }
        float rp = rr * cav;
        accR += rp;
        #pragma unroll
        for (int p = 0; p < 16; p++) {
            acc1[p] += rp * v[p];
            acc2[p] += rp * v[p] * v[p];
        }

        cA = nA; cB = nB; cC = nC; cD = nD; cav = nav;
    }

    // ---- R5-proven reduce: barrier-sequenced in-place adds per group ----
    if (wvin == 3) {
        float* r = buf[grp];
        r[32 * 64 + o] = accR;
        #pragma unroll
        for (int p = 0; p < 16; p++) r[p * 64 + o] = acc1[p];
        #pragma unroll
        for (int p = 0; p < 16; p++) r[(16 + p) * 64 + o] = acc2[p];
    }
    __syncthreads();
    if (wvin == 2) {
        float* r = buf[grp];
        r[32 * 64 + o] += accR;
        #pragma unroll
        for (int p = 0; p < 16; p++) r[p * 64 + o] += acc1[p];
        #pragma unroll
        for (int p = 0; p < 16; p++) r[(16 + p) * 64 + o] += acc2[p];
    }
    __syncthreads();
    if (wvin == 1) {
        float* r = buf[grp];
        r[32 * 64 + o] += accR;
        #pragma unroll
        for (int p = 0; p < 16; p++) r[p * 64 + o] += acc1[p];
        #pragma unroll
        for (int p = 0; p < 16; p++) r[(16 + p) * 64 + o] += acc2[p];
    }
    __syncthreads();
    if (wvin == 0) {
        float* r = buf[grp];
        r[32 * 64 + o] += accR;
        #pragma unroll
        for (int p = 0; p < 16; p++) r[p * 64 + o] += acc1[p];
        #pragma unroll
        for (int p = 0; p < 16; p++) r[(16 + p) * 64 + o] += acc2[p];
    }
    __syncthreads();

    // ---- ONE cooperative flush: ~2 coalesced atomics per thread ----
    float* ac = accum_out + (size_t)b * ACC_PER_B;
    for (int j = tid; j < ACC_PER_B; j += 1024)
        atomicAdd(ac + j, buf[0][j] + buf[1][j] + buf[2][j] + buf[3][j]);
}

__global__ __launch_bounds__(64) void stats_final(
    const float* __restrict__ accum,   // [B][33][64] summed
    const float* __restrict__ beta_v,  // [64]
    const float* __restrict__ beta_a,  // [64]
    float* __restrict__ out,
    float inv_temp)
{
    const int b = blockIdx.x;
    const int o = threadIdx.x;  // 64 threads = 1 wave
    const float* ac = accum + (size_t)b * ACC_PER_B;

    float rps = ac[32 * 64 + o];
    float rinv = 1.0f / rps;
    float m[16];
    float logsum = 0.f;
    #pragma unroll
    for (int p = 0; p < 16; p++) {
        float mm = ac[p * 64 + o] * rinv;
        float vv = fmaxf(ac[(16 + p) * 64 + o] * rinv - mm * mm, 0.f);
        m[p] = mm;
        logsum += __logf(sqrtf(vv) + EPSF);
    }
    float cost = rps * (16.0f * beta_v[o] + logsum);

    float cm = cost;
    #pragma unroll
    for (int s = 32; s > 0; s >>= 1) cm += __shfl_xor(cm, s, 64);
    cm *= (1.0f / 64.0f);
    float dd = cost - cm;
    float cs = dd * dd;
    #pragma unroll
    for (int s = 32; s > 0; s >>= 1) cs += __shfl_xor(cs, s, 64);
    cs = sqrtf(cs * (1.0f / 64.0f));

    float x = inv_temp * (beta_a[o] + (cm - cost) / (cs + EPSF));
    float oa = 1.0f / (1.0f + __expf(-x));

    float* op = out + ((size_t)b * 64 + o) * 16;
    #pragma unroll
    for (int p = 0; p < 16; p++) op[p] = m[p];
    out[(size_t)NB * NO * NP + (size_t)b * 64 + o] = oa;
}

extern "C" void kernel_launch(void* const* d_in, const int* in_sizes, int n_in,
                              void* d_out, int out_size, void* d_ws, size_t ws_size,
                              hipStream_t stream) {
    const float* pose   = (const float*)d_in[0];  // (32,8,8,32,4,4)
    const float* act    = (const float*)d_in[1];  // (32,8,8,32)
    const float* wmat   = (const float*)d_in[2];  // (32,64,4,4)
    const float* beta_v = (const float*)d_in[3];  // (1,64)
    const float* beta_a = (const float*)d_in[4];  // (1,64)
    float* out = (float*)d_out;
    float* ws = (float*)d_ws;

    float* a0 = ws;
    float* a1 = ws + (size_t)ACC_TOTAL;
    float* a2 = ws + 2 * (size_t)ACC_TOTAL;

    // zero the three atomic accumulators (ws is poisoned before every call)
    hipMemsetAsync(ws, 0, 3 * (size_t)ACC_TOTAL * sizeof(float), stream);

    dim3 grid(16, NB);   // 512 WGs x 1024 thd
    accum_kernel<true ><<<grid, 1024, 0, stream>>>(pose, act, wmat, beta_v, beta_a,
                                                   nullptr, a0, 0.0f);
    accum_kernel<false><<<grid, 1024, 0, stream>>>(pose, act, wmat, beta_v, beta_a,
                                                   a0, a1, 1.0f);
    accum_kernel<false><<<grid, 1024, 0, stream>>>(pose, act, wmat, beta_v, beta_a,
                                                   a1, a2, 2.0f);
    stats_final<<<NB, 64, 0, stream>>>(a2, beta_v, beta_a, out, 3.0f);
}